// Round 5
// baseline (689.614 us; speedup 1.0000x reference)
//
#include <hip/hip_runtime.h>
#include <hip/hip_bf16.h>

typedef __hip_bfloat16 bf16;
typedef __attribute__((ext_vector_type(8))) __bf16 bf16x8;
typedef __attribute__((ext_vector_type(4))) float  f32x4;

#define HW   65536
#define WID  256
#define CC   96
#define NB   4
static const size_t S_ELEMS = (size_t)NB * CC * HW;  // 25,165,824 elements

__device__ __forceinline__ float lo2f(unsigned u) { unsigned x = u << 16;        return __builtin_bit_cast(float, x); }
__device__ __forceinline__ float hi2f(unsigned u) { unsigned x = u & 0xffff0000u; return __builtin_bit_cast(float, x); }
__device__ __forceinline__ float b2f(bf16 v) { return __bfloat162float(v); }
__device__ __forceinline__ unsigned short f2bu(float f) {
    return __builtin_bit_cast(unsigned short, __float2bfloat16(f));
}

__device__ __forceinline__ void store8b(bf16* p, const float v[8]) {
    alignas(16) bf16 o[8];
#pragma unroll
    for (int i = 0; i < 8; ++i) o[i] = __float2bfloat16(v[i]);
    *reinterpret_cast<uint4*>(p) = *reinterpret_cast<const uint4*>(o);
}

// exact-GELU via Abramowitz-Stegun 7.1.26 erf (|err| < 1.5e-7)
__device__ __forceinline__ float gelu_erf(float v) {
    float z  = fabsf(v) * 0.70710678118654752f;
    float t  = __builtin_amdgcn_rcpf(1.f + 0.3275911f * z);
    float poly = t * (0.254829592f + t * (-0.284496736f + t * (1.421413741f
               + t * (-1.453152027f + t * 1.061405429f))));
    float erfz = 1.f - poly * __expf(-z * z);
    float erfv = copysignf(erfz, v);
    return 0.5f * v * (1.f + erfv);
}

// ---------------- Kernel 1: LayerNorm over channel dim of NCHW ----------------
__global__ __launch_bounds__(256) void ln_kernel(
    const float* __restrict__ x, const float* __restrict__ lw,
    const float* __restrict__ lb, bf16* __restrict__ y)
{
    int t  = blockIdx.x * 256 + threadIdx.x;   // [0, 131072)
    int b  = t >> 15;
    int hw = (t & 32767) * 2;
    size_t base = (size_t)b * CC * HW + hw;

    float s0 = 0.f, s1 = 0.f, q0 = 0.f, q1 = 0.f;
    for (int c = 0; c < CC; ++c) {
        float2 v = *reinterpret_cast<const float2*>(&x[base + (size_t)c * HW]);
        s0 += v.x; s1 += v.y; q0 += v.x * v.x; q1 += v.y * v.y;
    }
    float mu0 = s0 * (1.f / 96.f), mu1 = s1 * (1.f / 96.f);
    float rs0 = rsqrtf(q0 * (1.f / 96.f) - mu0 * mu0 + 1e-6f);
    float rs1 = rsqrtf(q1 * (1.f / 96.f) - mu1 * mu1 + 1e-6f);

    for (int c = 0; c < CC; ++c) {
        float2 v = *reinterpret_cast<const float2*>(&x[base + (size_t)c * HW]);
        float g = lw[c], be = lb[c];
        bf16 o[2];
        o[0] = __float2bfloat16((v.x - mu0) * rs0 * g + be);
        o[1] = __float2bfloat16((v.y - mu1) * rs1 * g + be);
        *reinterpret_cast<uint*>(&y[base + (size_t)c * HW]) = *reinterpret_cast<uint*>(o);
    }
}

// ---------------- conv1x1 via MFMA 16x16x32 bf16 ----------------
// Layouts (m89-verified): A[m=lane&15][k=quad*8+j]; B[k=quad*8+j][n=lane&15];
// D col=lane&15 (position), row=quad*4+reg (channel).
template <typename TI, typename TR, typename TOT, int CIN, int COUT, bool GELU, bool HASRES>
__global__ __launch_bounds__(256) void conv1x1_mfma(
    const TI* __restrict__ in, const float* __restrict__ wgt,
    const float* __restrict__ bias, const TR* __restrict__ resid,
    TOT* __restrict__ out)
{
    constexpr int CINP = CIN + 8;
    constexpr int MT   = COUT / 16;
    constexpr int KT   = CIN / 32;
    __shared__ unsigned short s_w[COUT * CINP];
    __shared__ float          s_b[COUT];

    const int tid  = threadIdx.x;
    const int lane = tid & 63;
    const int wave = tid >> 6;
    const int q    = lane >> 4;
    const int n    = lane & 15;

    const int pos0 = blockIdx.x * 128;
    const int b    = pos0 >> 16;
    const int hw0  = pos0 & 65535;

    constexpr int C4 = CIN / 4;
    for (int k = tid; k < COUT * C4; k += 256) {
        int o = k / C4, c4 = (k - o * C4) * 4;
        float4 w4 = *reinterpret_cast<const float4*>(&wgt[o * CIN + c4]);
        ushort4 pk = make_ushort4(f2bu(w4.x), f2bu(w4.y), f2bu(w4.z), f2bu(w4.w));
        *reinterpret_cast<ushort4*>(&s_w[o * CINP + c4]) = pk;
    }
    for (int k = tid; k < COUT; k += 256) s_b[k] = bias[k];
    __syncthreads();

    const TI* inb = in + (size_t)b * CIN * HW;
    const int p0  = hw0 + wave * 32 + n;
    const int p1  = p0 + 16;

    f32x4 acc[MT][2];
#pragma unroll
    for (int mt = 0; mt < MT; ++mt) {
        acc[mt][0] = {0.f, 0.f, 0.f, 0.f};
        acc[mt][1] = {0.f, 0.f, 0.f, 0.f};
    }

    for (int kt = 0; kt < KT; ++kt) {
        const int c0 = kt * 32 + q * 8;
        union { unsigned short u[8]; bf16x8 v; } bf0, bf1;
#pragma unroll
        for (int j = 0; j < 8; ++j) {
            const size_t rowo = (size_t)(c0 + j) * HW;
            if constexpr (__is_same(TI, float)) {
                bf0.u[j] = f2bu(inb[rowo + p0]);
                bf1.u[j] = f2bu(inb[rowo + p1]);
            } else {
                bf0.u[j] = *reinterpret_cast<const unsigned short*>(&inb[rowo + p0]);
                bf1.u[j] = *reinterpret_cast<const unsigned short*>(&inb[rowo + p1]);
            }
        }
#pragma unroll
        for (int mt = 0; mt < MT; ++mt) {
            union { unsigned short u[8]; bf16x8 v; } fa;
            *reinterpret_cast<uint4*>(fa.u) =
                *reinterpret_cast<const uint4*>(&s_w[(mt * 16 + n) * CINP + kt * 32 + q * 8]);
            acc[mt][0] = __builtin_amdgcn_mfma_f32_16x16x32_bf16(fa.v, bf0.v, acc[mt][0], 0, 0, 0);
            acc[mt][1] = __builtin_amdgcn_mfma_f32_16x16x32_bf16(fa.v, bf1.v, acc[mt][1], 0, 0, 0);
        }
    }

    const size_t obase = (size_t)b * COUT * HW;
#pragma unroll
    for (int mt = 0; mt < MT; ++mt) {
#pragma unroll
        for (int nt = 0; nt < 2; ++nt) {
            const int p = (nt == 0) ? p0 : p1;
#pragma unroll
            for (int r = 0; r < 4; ++r) {
                const int o = mt * 16 + q * 4 + r;
                float v = acc[mt][nt][r] + s_b[o];
                if constexpr (GELU) v = gelu_erf(v);
                const size_t idx = obase + (size_t)o * HW + p;
                if constexpr (HASRES) {
                    if constexpr (__is_same(TR, float)) v += resid[idx];
                    else                                v += b2f(resid[idx]);
                }
                if constexpr (__is_same(TOT, float)) out[idx] = v;
                else                                 out[idx] = __float2bfloat16(v);
            }
        }
    }
}

// ---------------- Kernel 3: experts, 16-px register windows + prefetch ----------------
// Thread: 16 consecutive w outputs at one (b,c,h). Window [w0-8,w0+24) = 4 aligned
// 16B chunks, each fully valid or fully OOB. Two packed buffers; next row's loads
// are issued before the current row's unpack+FMA (software pipeline).
struct Pk { uint4 x[4]; };

__device__ __forceinline__ Pk load_win(const bf16* rowbase, int w0, bool rowok)
{
    const uint4 z = make_uint4(0u, 0u, 0u, 0u);
    const uint4* p = reinterpret_cast<const uint4*>(rowbase + w0 - 8);
    Pk r;
    r.x[0] = (rowok && w0 > 0)   ? p[0] : z;   // px [w0-8, w0)
    r.x[1] =  rowok              ? p[1] : z;   // px [w0,   w0+8)
    r.x[2] =  rowok              ? p[2] : z;   // px [w0+8, w0+16)
    r.x[3] = (rowok && w0 < 240) ? p[3] : z;   // px [w0+16,w0+24)
    return r;
}
__device__ __forceinline__ void unpack32(const Pk& p, float w[32])
{
#pragma unroll
    for (int j = 0; j < 4; ++j) {
        const uint4& u = p.x[j];
        w[j*8+0]=lo2f(u.x); w[j*8+1]=hi2f(u.x); w[j*8+2]=lo2f(u.y); w[j*8+3]=hi2f(u.y);
        w[j*8+4]=lo2f(u.z); w[j*8+5]=hi2f(u.z); w[j*8+6]=lo2f(u.w); w[j*8+7]=hi2f(u.w);
    }
}
template <int NT, int DIL>
__device__ __forceinline__ void applyN(const float* wk, const float win[32], float* acc)
{
#pragma unroll
    for (int t = 0; t < NT; ++t) {
        float wv = wk[t];
        const int off = (t - NT / 2) * DIL;
#pragma unroll
        for (int o = 0; o < 16; ++o) acc[o] += wv * win[8 + o + off];
    }
}

__global__ __launch_bounds__(256) void experts_kernel(
    const bf16* __restrict__ xn, const bf16* __restrict__ t0,
    const float* __restrict__ w0, const float* __restrict__ b0,
    const float* __restrict__ w1, const float* __restrict__ b1,
    const float* __restrict__ w2, const float* __restrict__ b2,
    const float* __restrict__ sw, const float* __restrict__ prompt,
    bf16* __restrict__ xa)
{
    const int tid = threadIdx.x;
    const int wg  = tid & 15;          // 16-px group
    const int r   = tid >> 4;          // row in 16-row strip
    const int bid = blockIdx.x;
    const int hs  = bid & 15;
    const int bc  = bid >> 4;          // b*96 + c
    const int b   = bc / 96;
    const int c   = bc - b * 96;
    const int h   = hs * 16 + r;
    const int w0p = wg * 16;
    const size_t pbase = (size_t)bc * HW;
    const bf16* xp = xn + pbase;
    const bf16* tp = t0 + pbase;

    // block-uniform weights -> scalar registers
    float wk0[9], wk1[9], wk2[25];
#pragma unroll
    for (int i = 0; i < 9; ++i)  wk0[i] = w0[c * 9 + i];
#pragma unroll
    for (int i = 0; i < 9; ++i)  wk1[i] = w1[c * 9 + i];
#pragma unroll
    for (int i = 0; i < 25; ++i) wk2[i] = w2[c * 25 + i];

    float acc0[16], acc1[16], acc2[16];
    {
        float bb0 = b0[c], bb1 = b1[c], bb2 = b2[c];
#pragma unroll
        for (int o = 0; o < 16; ++o) { acc0[o] = bb0; acc1[o] = bb1; acc2[o] = bb2; }
    }

    float win[32];
    // pipeline: load row i+1 before applying row i
    Pk pA = load_win(xp + (h - 6) * WID, w0p, h >= 6);
    Pk pB = load_win(xp + (h - 3) * WID, w0p, h >= 3);

    unpack32(pA, win); applyN<5,3>(&wk2[0],  win, acc2);
    pA = load_win(xp + (h - 2) * WID, w0p, h >= 2);
    unpack32(pB, win); applyN<5,3>(&wk2[5],  win, acc2);
    pB = load_win(xp + h * WID, w0p, true);
    unpack32(pA, win); applyN<3,2>(&wk1[0],  win, acc1);
    pA = load_win(xp + (h + 2) * WID, w0p, h < 254);
    unpack32(pB, win); applyN<3,2>(&wk1[3],  win, acc1);
                       applyN<5,3>(&wk2[10], win, acc2);
    pB = load_win(xp + (h + 3) * WID, w0p, h < 253);
    unpack32(pA, win); applyN<3,2>(&wk1[6],  win, acc1);
    pA = load_win(xp + (h + 6) * WID, w0p, h < 250);
    unpack32(pB, win); applyN<5,3>(&wk2[15], win, acc2);
    pB = load_win(tp + (h - 1) * WID, w0p, h >= 1);
    unpack32(pA, win); applyN<5,3>(&wk2[20], win, acc2);
    pA = load_win(tp + h * WID, w0p, true);
    unpack32(pB, win); applyN<3,1>(&wk0[0],  win, acc0);
    pB = load_win(tp + (h + 1) * WID, w0p, h < 255);
    unpack32(pA, win); applyN<3,1>(&wk0[3],  win, acc0);
    unpack32(pB, win); applyN<3,1>(&wk0[6],  win, acc0);

    const float s0 = sw[b * 3 + 0], s1 = sw[b * 3 + 1], s2 = sw[b * 3 + 2];
    const float pr = 1.f + prompt[b * 96 + c];
    float ov[16];
#pragma unroll
    for (int o = 0; o < 16; ++o)
        ov[o] = (s0 * acc0[o] + s1 * acc1[o] + s2 * acc2[o]) * pr;
    store8b(&xa[pbase + h * WID + w0p],     &ov[0]);
    store8b(&xa[pbase + h * WID + w0p + 8], &ov[8]);
}

// ---------------- launch ----------------
extern "C" void kernel_launch(void* const* d_in, const int* in_sizes, int n_in,
                              void* d_out, int out_size, void* d_ws, size_t ws_size,
                              hipStream_t stream)
{
    const float* x       = (const float*)d_in[0];
    const float* prompt  = (const float*)d_in[1];
    const float* sw      = (const float*)d_in[2];
    const float* ln_w    = (const float*)d_in[3];
    const float* ln_b    = (const float*)d_in[4];
    const float* e0_pw_w = (const float*)d_in[5];
    const float* e0_pw_b = (const float*)d_in[6];
    const float* e0_dw_w = (const float*)d_in[7];
    const float* e0_dw_b = (const float*)d_in[8];
    const float* e1_dw_w = (const float*)d_in[9];
    const float* e1_dw_b = (const float*)d_in[10];
    const float* e2_dw_w = (const float*)d_in[11];
    const float* e2_dw_b = (const float*)d_in[12];
    const float* proj_w  = (const float*)d_in[13];
    const float* proj_b  = (const float*)d_in[14];
    const float* ffn1_w  = (const float*)d_in[15];
    const float* ffn1_b  = (const float*)d_in[16];
    const float* ffn2_w  = (const float*)d_in[17];
    const float* ffn2_b  = (const float*)d_in[18];

    float* out = (float*)d_out;
    bf16*  ws  = (bf16*)d_ws;
    bf16*  A   = ws;                 // xn bf16 (48 MB); later x1 bf16
    bf16*  Bt  = ws + S_ELEMS;       // t0 bf16 (48 MB); later h (96 MB, spans Bt+Cx)
    bf16*  Cx  = ws + 2 * S_ELEMS;   // xa bf16 (48 MB)  -> peak ws = 144 MB

    // 1) xn = LayerNorm_c(x)
    ln_kernel<<<512, 256, 0, stream>>>(x, ln_w, ln_b, A);
    // 2) t0 = conv1x1(xn, e0_pw)
    conv1x1_mfma<bf16, float, bf16, 96, 96, false, false>
        <<<2048, 256, 0, stream>>>(A, e0_pw_w, e0_pw_b, (const float*)nullptr, Bt);
    // 3) xa = (s0*dw3(t0) + s1*dw3d2(xn) + s2*dw5d3(xn)) * (1+prompt)
    experts_kernel<<<6144, 256, 0, stream>>>(A, Bt, e0_dw_w, e0_dw_b, e1_dw_w, e1_dw_b,
                                             e2_dw_w, e2_dw_b, sw, prompt, Cx);
    // 4) x1 = x + conv1x1(xa, proj)  -> A (bf16; xn dead)
    conv1x1_mfma<bf16, float, bf16, 96, 96, false, true>
        <<<2048, 256, 0, stream>>>(Cx, proj_w, proj_b, x, A);
    // 5) h = gelu(conv1x1(x1, ffn1)) -> Bt..Cx (96 MB; t0/xa dead)
    conv1x1_mfma<bf16, float, bf16, 96, 192, true, false>
        <<<2048, 256, 0, stream>>>(A, ffn1_w, ffn1_b, (const float*)nullptr, Bt);
    // 6) out = x1 + conv1x1(h, ffn2) -> d_out (fp32)
    conv1x1_mfma<bf16, bf16, float, 192, 96, false, true>
        <<<2048, 256, 0, stream>>>(Bt, ffn2_w, ffn2_b, A, out);
}